// Round 2
// baseline (53.840 us; speedup 1.0000x reference)
//
#include <hip/hip_runtime.h>
#include <math.h>

#define NROWS 65536
#define NCLS  1000
#define ALPHA 1.0f
#define BETA  1.5f

// Kernel 1: one 64-lane wave per row. Single HBM pass: load 1000 floats
// (250 float4) into registers, wave-reduce max, exp-sum from registers,
// then CE + atomic accumulate into per-class sums/counts.
__global__ __launch_bounds__(256) void ce_rows_kernel(
    const float* __restrict__ inp, const int* __restrict__ tgt,
    float* __restrict__ sums, float* __restrict__ counts)
{
    const int wave = threadIdx.x >> 6;
    const int lane = threadIdx.x & 63;
    const int row  = blockIdx.x * 4 + wave;
    if (row >= NROWS) return;

    const float4* rp = reinterpret_cast<const float4*>(inp + (size_t)row * NCLS);

    // 250 float4 chunks per row; lane handles chunks lane + 64*k, k=0..3
    // (k=3 exists only for lane < 58 since 250 = 3*64 + 58).
    float4 v[4];
    const bool has4 = (lane < 58);
#pragma unroll
    for (int k = 0; k < 3; ++k) v[k] = rp[lane + 64 * k];
    v[3] = has4 ? rp[lane + 192]
                : make_float4(-INFINITY, -INFINITY, -INFINITY, -INFINITY);

    // lane-local max
    float m = -INFINITY;
#pragma unroll
    for (int k = 0; k < 4; ++k) {
        m = fmaxf(m, fmaxf(fmaxf(v[k].x, v[k].y), fmaxf(v[k].z, v[k].w)));
    }
    // wave max reduce (64 lanes)
#pragma unroll
    for (int off = 32; off > 0; off >>= 1)
        m = fmaxf(m, __shfl_xor(m, off));

    // exp-sum from registers (exp(-inf - m) == 0, so padding is harmless)
    float s = 0.f;
#pragma unroll
    for (int k = 0; k < 4; ++k) {
        s += __expf(v[k].x - m);
        s += __expf(v[k].y - m);
        s += __expf(v[k].z - m);
        s += __expf(v[k].w - m);
    }
#pragma unroll
    for (int off = 32; off > 0; off >>= 1)
        s += __shfl_xor(s, off);

    if (lane == 0) {
        const int t = tgt[row];
        const float picked = inp[(size_t)row * NCLS + t];
        const float ce = m + logf(s) - picked;
        atomicAdd(&sums[t], ce);
        atomicAdd(&counts[t], 1.0f);
    }
}

// Kernel 2: single block. losses = sums/counts; mean; unbiased std;
// sigmoid scale; weighted sum -> out[0].
__global__ __launch_bounds__(1024) void finalize_kernel(
    const float* __restrict__ sums, const float* __restrict__ counts,
    float* __restrict__ out)
{
    __shared__ float red[1024];
    __shared__ float losses_s[NCLS];
    const int t = threadIdx.x;

    float l = 0.f;
    if (t < NCLS) {
        l = sums[t] / counts[t];
        losses_s[t] = l;
    }

    // sum(losses)
    red[t] = (t < NCLS) ? l : 0.f;
    __syncthreads();
#pragma unroll
    for (int off = 512; off > 0; off >>= 1) {
        if (t < off) red[t] += red[t + off];
        __syncthreads();
    }
    const float mean = red[0] / (float)NCLS;
    __syncthreads();   // everyone has read red[0] before we overwrite

    // sum((losses-mean)^2)
    float d = (t < NCLS) ? (losses_s[t] - mean) : 0.f;
    red[t] = d * d;
    __syncthreads();
#pragma unroll
    for (int off = 512; off > 0; off >>= 1) {
        if (t < off) red[t] += red[t + off];
        __syncthreads();
    }
    const float var = red[0] / (float)(NCLS - 1);
    const float inv_std = 1.0f / sqrtf(var);
    __syncthreads();

    // sum(losses * scale)
    float contrib = 0.f;
    if (t < NCLS) {
        const float norm = (losses_s[t] - mean) * inv_std;
        const float scale = BETA / (1.0f + __expf(-norm / ALPHA)) - BETA * 0.5f + 1.0f;
        contrib = losses_s[t] * scale;
    }
    red[t] = contrib;
    __syncthreads();
#pragma unroll
    for (int off = 512; off > 0; off >>= 1) {
        if (t < off) red[t] += red[t + off];
        __syncthreads();
    }
    if (t == 0) out[0] = red[0];
}

extern "C" void kernel_launch(void* const* d_in, const int* in_sizes, int n_in,
                              void* d_out, int out_size, void* d_ws, size_t ws_size,
                              hipStream_t stream)
{
    const float* inp = (const float*)d_in[0];
    const int*   tgt = (const int*)d_in[1];
    float* out = (float*)d_out;

    float* sums   = (float*)d_ws;
    float* counts = sums + NCLS;

    // ws is poisoned (0xAA) once and never re-poisoned -> zero it each call.
    hipMemsetAsync(d_ws, 0, 2 * NCLS * sizeof(float), stream);

    ce_rows_kernel<<<NROWS / 4, 256, 0, stream>>>(inp, tgt, sums, counts);
    finalize_kernel<<<1, 1024, 0, stream>>>(sums, counts, out);
}